// Round 11
// baseline (499.434 us; speedup 1.0000x reference)
//
#include <hip/hip_runtime.h>

#define NEG_SLOPE 0.2f
#define NG 8
#define CH 64   // edge chunk per wave (lane-parallel weight phase)

typedef unsigned short ushort_t;
typedef __attribute__((ext_vector_type(8))) short short8v;   // 8 bf16 (4 VGPRs)
typedef __attribute__((ext_vector_type(4))) float f32x4;     // MFMA C/D frag

__device__ __forceinline__ float lrelu(float x) { return x > 0.f ? x : NEG_SLOPE * x; }
__device__ __forceinline__ float eluf(float x) { return x > 0.f ? x : expm1f(x); }
__device__ __forceinline__ float wave_sum(float v) {
    #pragma unroll
    for (int o = 32; o; o >>= 1) v += __shfl_xor(v, o);
    return v;
}
// f32 <-> bf16 (RNE), finite inputs only
__device__ __forceinline__ ushort_t f2bf(float f) {
    unsigned u = __float_as_uint(f);
    unsigned r = (u + 0x7FFFu + ((u >> 16) & 1u)) >> 16;
    return (ushort_t)r;
}
__device__ __forceinline__ float bf2f(ushort_t s) {
    return __uint_as_float(((unsigned)s) << 16);
}

// ---------------- CSR build ----------------------------------------------------
__global__ __launch_bounds__(256) void k_hist(const int* __restrict__ ei,
                                              int* __restrict__ deg, int E) {
    int e = blockIdx.x * 256 + threadIdx.x;
    if (e < E) atomicAdd(&deg[ei[E + e]], 1);
}

__global__ __launch_bounds__(256) void k_scanA(const int* __restrict__ deg,
                                               int* __restrict__ bsum, int N) {
    __shared__ int wsums[4];
    int b = blockIdx.x, t = threadIdx.x;
    int base = b * 1024 + t * 4;
    int s = 0;
    #pragma unroll
    for (int k = 0; k < 4; k++) { int i = base + k; if (i < N) s += deg[i]; }
    #pragma unroll
    for (int o = 32; o; o >>= 1) s += __shfl_xor(s, o);
    if ((t & 63) == 0) wsums[t >> 6] = s;
    __syncthreads();
    if (t == 0) bsum[b] = wsums[0] + wsums[1] + wsums[2] + wsums[3];
}

__global__ __launch_bounds__(64) void k_scanB(const int* __restrict__ bsum,
                                              int* __restrict__ boff,
                                              int* __restrict__ rpN, int SB) {
    int lane = threadIdx.x;
    int own = (lane < SB) ? bsum[lane] : 0;
    int v = own;
    #pragma unroll
    for (int o = 1; o < 64; o <<= 1) { int y = __shfl_up(v, o); if (lane >= o) v += y; }
    if (lane < SB) boff[lane] = v - own;
    if (lane == 63) *rpN = v;
}

__global__ __launch_bounds__(256) void k_scanC(const int* __restrict__ deg,
                                               const int* __restrict__ boff,
                                               int* __restrict__ rp,
                                               int* __restrict__ cur, int N) {
    __shared__ int wtot[4];
    int b = blockIdx.x, t = threadIdx.x;
    int wid = t >> 6, lane = t & 63;
    int base = b * 1024 + t * 4;
    int d[4];
    #pragma unroll
    for (int k = 0; k < 4; k++) d[k] = (base + k < N) ? deg[base + k] : 0;
    int tsum = d[0] + d[1] + d[2] + d[3];
    int v = tsum;
    #pragma unroll
    for (int o = 1; o < 64; o <<= 1) { int y = __shfl_up(v, o); if (lane >= o) v += y; }
    if (lane == 63) wtot[wid] = v;
    __syncthreads();
    int wbase = 0;
    for (int k = 0; k < wid; k++) wbase += wtot[k];
    int run = boff[b] + wbase + v - tsum;
    #pragma unroll
    for (int k = 0; k < 4; k++) {
        if (base + k < N) { rp[base + k] = run; cur[base + k] = run; }
        run += d[k];
    }
}

__global__ __launch_bounds__(256) void k_fill(const int* __restrict__ ei,
                                              int* __restrict__ cur,
                                              int* __restrict__ csr, int E) {
    int e = blockIdx.x * 256 + threadIdx.x;
    if (e >= E) return;
    int s = ei[e], d = ei[E + e];
    int pos = atomicAdd(&cur[d], 1);
    csr[pos] = s;
}

// ------- W1 -> bf16 hi/lo in MFMA-fragment order --------------------------------
__global__ __launch_bounds__(256) void k_w1t(const float* __restrict__ W1,
                                             ushort_t* __restrict__ w1th,
                                             ushort_t* __restrict__ w1tl) {
    int tile = blockIdx.x >> 3, ks = blockIdx.x & 7;   // 128 blocks
    for (int i = threadIdx.x; i < 512; i += 256) {
        int lane = i >> 3, e = i & 7;
        int jl = lane & 15, q = lane >> 4;
        int col = tile * 16 + jl;
        int k = ks * 32 + 8 * q + e;
        float w = W1[(size_t)k * 256 + col];
        ushort_t hi = f2bf(w);
        float lo = w - bf2f(hi);
        size_t o = (size_t)blockIdx.x * 512 + i;
        w1th[o] = hi;
        w1tl[o] = f2bf(lo);
    }
}

// ------- GEMM1 via split-bf16 MFMA (R7-proven): xw1 = x @ W1 + al/ar epilogue ---
__global__ __launch_bounds__(256, 4) void k_gemm1(const float* __restrict__ x,
                                               const ushort_t* __restrict__ w1th,
                                               const ushort_t* __restrict__ w1tl,
                                               const float* __restrict__ a_s,
                                               const float* __restrict__ a_d,
                                               ushort_t* __restrict__ xw1b,
                                               float* __restrict__ al4,
                                               float* __restrict__ ar4, int N) {
    __shared__ __align__(16) unsigned char smem[33792];
    ushort_t* xh = (ushort_t*)smem;
    ushort_t* xl = (ushort_t*)(smem + 16896);
    int r0 = blockIdx.x * 32;
    int tid = threadIdx.x;
    int lane = tid & 63, wv = tid >> 6;
    // ---- stage x -> bf16 hi/lo in LDS ----
    for (int i = tid; i < 2048; i += 256) {
        int r = i >> 6, k4 = (i & 63) << 2;
        float4 v = (r0 + r < N) ? *(const float4*)(x + (size_t)(r0 + r) * 256 + k4)
                                : make_float4(0.f, 0.f, 0.f, 0.f);
        ushort4 h4, l4;
        h4.x = f2bf(v.x); l4.x = f2bf(v.x - bf2f(h4.x));
        h4.y = f2bf(v.y); l4.y = f2bf(v.y - bf2f(h4.y));
        h4.z = f2bf(v.z); l4.z = f2bf(v.z - bf2f(h4.z));
        h4.w = f2bf(v.w); l4.w = f2bf(v.w - bf2f(h4.w));
        *(ushort4*)(&xh[r * 264 + k4]) = h4;
        *(ushort4*)(&xl[r * 264 + k4]) = l4;
    }
    __syncthreads();
    // ---- MFMA K-loop ----
    int wr = wv & 1, wc = wv >> 1;       // 2x2 wave grid
    int jl = lane & 15, q = lane >> 4;
    f32x4 acc[8];
    #pragma unroll
    for (int t = 0; t < 8; t++) acc[t] = (f32x4){0.f, 0.f, 0.f, 0.f};
    const ushort_t* xhp = &xh[(16 * wr + jl) * 264];
    const ushort_t* xlp = &xl[(16 * wr + jl) * 264];
    const ushort_t* bhb = w1th + (size_t)wc * 32768 + lane * 8;
    const ushort_t* blb = w1tl + (size_t)wc * 32768 + lane * 8;
    #pragma unroll 1
    for (int ks = 0; ks < 8; ks++) {
        int ko = 32 * ks + 8 * q;
        short8v ah = *(const short8v*)(xhp + ko);
        short8v alo = *(const short8v*)(xlp + ko);
        #pragma unroll
        for (int tp = 0; tp < 4; tp++) {
            int t0 = 2 * tp, t1 = 2 * tp + 1;
            short8v bh0 = *(const short8v*)(bhb + (t0 * 8 + ks) * 512);
            short8v bl0 = *(const short8v*)(blb + (t0 * 8 + ks) * 512);
            short8v bh1 = *(const short8v*)(bhb + (t1 * 8 + ks) * 512);
            short8v bl1 = *(const short8v*)(blb + (t1 * 8 + ks) * 512);
            acc[t0] = __builtin_amdgcn_mfma_f32_16x16x32_bf16(ah, bh0, acc[t0], 0, 0, 0);
            acc[t0] = __builtin_amdgcn_mfma_f32_16x16x32_bf16(ah, bl0, acc[t0], 0, 0, 0);
            acc[t0] = __builtin_amdgcn_mfma_f32_16x16x32_bf16(alo, bh0, acc[t0], 0, 0, 0);
            acc[t1] = __builtin_amdgcn_mfma_f32_16x16x32_bf16(ah, bh1, acc[t1], 0, 0, 0);
            acc[t1] = __builtin_amdgcn_mfma_f32_16x16x32_bf16(ah, bl1, acc[t1], 0, 0, 0);
            acc[t1] = __builtin_amdgcn_mfma_f32_16x16x32_bf16(alo, bh1, acc[t1], 0, 0, 0);
        }
    }
    __syncthreads();                     // everyone done reading xh/xl
    // ---- D frags -> LDS f32 [32][256] ----
    float* outb = (float*)smem;
    #pragma unroll
    for (int t = 0; t < 8; t++) {
        int c = 128 * wc + 16 * t + jl;
        int rb = 16 * wr + 4 * q;
        outb[(rb + 0) * 256 + c] = acc[t].x;
        outb[(rb + 1) * 256 + c] = acc[t].y;
        outb[(rb + 2) * 256 + c] = acc[t].z;
        outb[(rb + 3) * 256 + c] = acc[t].w;
    }
    __syncthreads();
    // ---- epilogue (proven structure): al/ar + bf16 repack + coalesced store ----
    int c4 = lane << 2;
    int h = lane >> 4, kk = c4 & 63;
    float4 s4 = *(const float4*)(a_s + h * 64 + kk);
    float4 d4 = *(const float4*)(a_d + h * 64 + kk);
    float4 hv[8];
    #pragma unroll
    for (int t2 = 0; t2 < 8; t2++)
        hv[t2] = *(const float4*)(&outb[(wv + 4 * t2) * 256 + c4]);
    #pragma unroll
    for (int t2 = 0; t2 < 8; t2++) {
        float sl = hv[t2].x * s4.x + hv[t2].y * s4.y + hv[t2].z * s4.z + hv[t2].w * s4.w;
        float sr = hv[t2].x * d4.x + hv[t2].y * d4.y + hv[t2].z * d4.z + hv[t2].w * d4.w;
        #pragma unroll
        for (int o = 1; o < 16; o <<= 1) { sl += __shfl_xor(sl, o); sr += __shfl_xor(sr, o); }
        int r = r0 + wv + 4 * t2;
        if ((lane & 15) == 0 && r < N) {
            al4[(size_t)r * 4 + h] = sl;
            ar4[(size_t)r * 4 + h] = sr;
        }
    }
    __syncthreads();                     // all reads of outb complete
    ushort_t* Ls = (ushort_t*)smem;      // [32][256]
    #pragma unroll
    for (int t2 = 0; t2 < 8; t2++) {
        int rl = wv + 4 * t2;
        Ls[rl * 256 + (kk + 0) * 4 + h] = f2bf(hv[t2].x);
        Ls[rl * 256 + (kk + 1) * 4 + h] = f2bf(hv[t2].y);
        Ls[rl * 256 + (kk + 2) * 4 + h] = f2bf(hv[t2].z);
        Ls[rl * 256 + (kk + 3) * 4 + h] = f2bf(hv[t2].w);
    }
    __syncthreads();
    #pragma unroll
    for (int p = 0; p < 4; p++) {
        int flat = p * 2048 + tid * 8;   // 8 ushorts = 16 B per thread
        int rl = flat >> 8, col = flat & 255;
        int r = r0 + rl;
        if (r < N)
            *(uint4*)(xw1b + (size_t)r * 256 + col) = *(const uint4*)(Ls + flat);
    }
}

__device__ __forceinline__ float4 wexp4(float4 a, float4 arn) {
    float4 w;
    w.x = __expf(lrelu(a.x + arn.x));
    w.y = __expf(lrelu(a.y + arn.y));
    w.z = __expf(lrelu(a.z + arn.z));
    w.w = __expf(lrelu(a.w + arn.w));
    return w;
}

// weight phase for one chunk: csr -> al4 -> exp -> LDS (dependent ~600cy chain)
__device__ __forceinline__ void wchunk(int cs, int cnt, int lane,
                                       const int* __restrict__ csr,
                                       const float* __restrict__ al4,
                                       float4 arn,
                                       float4* __restrict__ wb,
                                       int* __restrict__ sb,
                                       float& px, float& py, float& pz, float& pw) {
    if (lane < cnt) {
        int s = csr[cs + lane];
        float4 A = *(const float4*)(al4 + (size_t)s * 4);
        float4 w = wexp4(A, arn);
        sb[lane] = s;
        wb[lane] = w;
        px += w.x; py += w.y; pz += w.z; pw += w.w;
    }
}

// gather phase for one chunk (R7-proven depth-4 loop; no local arrays)
__device__ __forceinline__ void gchunk(int cnt, int lane,
                                       const ushort_t* __restrict__ xw1b,
                                       const float4* __restrict__ wb,
                                       const int* __restrict__ sb,
                                       float& a0, float& a1, float& a2, float& a3) {
    int jj = 0;
    for (; jj + 4 <= cnt; jj += 4) {
        int s0 = sb[jj],     s1 = sb[jj + 1];
        int s2 = sb[jj + 2], s3 = sb[jj + 3];
        float4 w0 = wb[jj],     w1 = wb[jj + 1];
        float4 w2 = wb[jj + 2], w3 = wb[jj + 3];
        ushort4 v0 = *(const ushort4*)(xw1b + (size_t)s0 * 256 + lane * 4);
        ushort4 v1 = *(const ushort4*)(xw1b + (size_t)s1 * 256 + lane * 4);
        ushort4 v2 = *(const ushort4*)(xw1b + (size_t)s2 * 256 + lane * 4);
        ushort4 v3 = *(const ushort4*)(xw1b + (size_t)s3 * 256 + lane * 4);
        a0 += w0.x * bf2f(v0.x) + w1.x * bf2f(v1.x) + w2.x * bf2f(v2.x) + w3.x * bf2f(v3.x);
        a1 += w0.y * bf2f(v0.y) + w1.y * bf2f(v1.y) + w2.y * bf2f(v2.y) + w3.y * bf2f(v3.y);
        a2 += w0.z * bf2f(v0.z) + w1.z * bf2f(v1.z) + w2.z * bf2f(v2.z) + w3.z * bf2f(v3.z);
        a3 += w0.w * bf2f(v0.w) + w1.w * bf2f(v1.w) + w2.w * bf2f(v2.w) + w3.w * bf2f(v3.w);
    }
    for (; jj < cnt; jj++) {
        int s = sb[jj];
        float4 w = wb[jj];
        ushort4 v = *(const ushort4*)(xw1b + (size_t)s * 256 + lane * 4);
        a0 += w.x * bf2f(v.x);
        a1 += w.y * bf2f(v.y);
        a2 += w.z * bf2f(v.z);
        a3 += w.w * bf2f(v.w);
    }
}

// ------- layer-1 aggregate: 2 nodes/wave, cross-node weight-phase pipelining ----
// R11: both nodes' first-chunk weight chains (csr->al4->exp, ~600cy, 16/64 lanes
// active) issue back-to-back into separate LDS buffers before either gather --
// B's chain hides under A's gather. Per-node arithmetic order unchanged ->
// bit-identical. Shared-W2 phase 2 as before.
__global__ __launch_bounds__(256, 8) void k_agg4(const int* __restrict__ rp,
                                                 const int* __restrict__ csr,
                                                 const float* __restrict__ al4,
                                                 const float* __restrict__ ar4,
                                                 const ushort_t* __restrict__ xw1b,
                                                 const float* __restrict__ b1,
                                                 const float* __restrict__ W2,
                                                 const float* __restrict__ as2,
                                                 const float* __restrict__ ad2,
                                                 ushort_t* __restrict__ xw2b,
                                                 float* __restrict__ al2,
                                                 float* __restrict__ ar2, int N) {
    __shared__ float hs[4][512];         // 2 nodes x 256 per wave
    __shared__ float4 wbuf[4][2][CH];    // per-wave, per-node weight buffers
    __shared__ int sbuf[4][2][CH];
    int wIdx = threadIdx.x >> 6;
    int w = (blockIdx.x * 256 + threadIdx.x) >> 6;
    int lane = threadIdx.x & 63;
    int nA = 2 * w, nB = 2 * w + 1;
    if (nA >= N) return;
    bool hasB = (nB < N);
    // ---- node A init + weight chunk 0 ----
    int e0A = rp[nA], e1A = rp[nA + 1];
    float4 arnA = *(const float4*)(ar4 + (size_t)nA * 4);
    float4 alnA = *(const float4*)(al4 + (size_t)nA * 4);
    float4 wsfA = wexp4(alnA, arnA);
    ushort4 svA = *(const ushort4*)(xw1b + (size_t)nA * 256 + lane * 4);
    float a0A = wsfA.x * bf2f(svA.x);
    float a1A = wsfA.y * bf2f(svA.y);
    float a2A = wsfA.z * bf2f(svA.z);
    float a3A = wsfA.w * bf2f(svA.w);
    float pxA = 0.f, pyA = 0.f, pzA = 0.f, pwA = 0.f;
    int cA0 = min(CH, e1A - e0A);
    wchunk(e0A, cA0, lane, csr, al4, arnA, wbuf[wIdx][0], sbuf[wIdx][0],
           pxA, pyA, pzA, pwA);
    // ---- node B init + weight chunk 0 (independent chain, overlaps A's) ----
    int e0B = 0, e1B = 0, cB0 = 0;
    float4 arnB = make_float4(0.f, 0.f, 0.f, 0.f);
    float4 wsfB = make_float4(0.f, 0.f, 0.f, 0.f);
    float a0B = 0.f, a1B = 0.f, a2B = 0.f, a3B = 0.f;
    float pxB = 0.f, pyB = 0.f, pzB = 0.f, pwB = 0.f;
    if (hasB) {
        e0B = rp[nB]; e1B = rp[nB + 1];
        arnB = *(const float4*)(ar4 + (size_t)nB * 4);
        float4 alnB = *(const float4*)(al4 + (size_t)nB * 4);
        wsfB = wexp4(alnB, arnB);
        ushort4 svB = *(const ushort4*)(xw1b + (size_t)nB * 256 + lane * 4);
        a0B = wsfB.x * bf2f(svB.x);
        a1B = wsfB.y * bf2f(svB.y);
        a2B = wsfB.z * bf2f(svB.z);
        a3B = wsfB.w * bf2f(svB.w);
        cB0 = min(CH, e1B - e0B);
        wchunk(e0B, cB0, lane, csr, al4, arnB, wbuf[wIdx][1], sbuf[wIdx][1],
               pxB, pyB, pzB, pwB);
    }
    // single drain covers both nodes' weight stores (per-wave LDS is in-order)
    asm volatile("s_waitcnt lgkmcnt(0)" ::: "memory");
    // ---- gather A (chunk 0 prestaged; rare extra chunks inline) ----
    gchunk(cA0, lane, xw1b, wbuf[wIdx][0], sbuf[wIdx][0], a0A, a1A, a2A, a3A);
    for (int cs = e0A + CH; cs < e1A; cs += CH) {
        int cnt = min(CH, e1A - cs);
        wchunk(cs, cnt, lane, csr, al4, arnA, wbuf[wIdx][0], sbuf[wIdx][0],
               pxA, pyA, pzA, pwA);
        asm volatile("s_waitcnt lgkmcnt(0)" ::: "memory");
        gchunk(cnt, lane, xw1b, wbuf[wIdx][0], sbuf[wIdx][0], a0A, a1A, a2A, a3A);
    }
    // ---- gather B ----
    if (hasB) {
        gchunk(cB0, lane, xw1b, wbuf[wIdx][1], sbuf[wIdx][1], a0B, a1B, a2B, a3B);
        for (int cs = e0B + CH; cs < e1B; cs += CH) {
            int cnt = min(CH, e1B - cs);
            wchunk(cs, cnt, lane, csr, al4, arnB, wbuf[wIdx][1], sbuf[wIdx][1],
                   pxB, pyB, pzB, pwB);
            asm volatile("s_waitcnt lgkmcnt(0)" ::: "memory");
            gchunk(cnt, lane, xw1b, wbuf[wIdx][1], sbuf[wIdx][1], a0B, a1B, a2B, a3B);
        }
    }
    // ---- finish A ----
    {
        float wx = wave_sum(pxA) + wsfA.x;
        float wy = wave_sum(pyA) + wsfA.y;
        float wz = wave_sum(pzA) + wsfA.z;
        float ww = wave_sum(pwA) + wsfA.w;
        hs[wIdx][lane]       = eluf(a0A / wx + b1[lane]);
        hs[wIdx][64 + lane]  = eluf(a1A / wy + b1[64 + lane]);
        hs[wIdx][128 + lane] = eluf(a2A / wz + b1[128 + lane]);
        hs[wIdx][192 + lane] = eluf(a3A / ww + b1[192 + lane]);
    }
    // ---- finish B ----
    if (hasB) {
        float wx = wave_sum(pxB) + wsfB.x;
        float wy = wave_sum(pyB) + wsfB.y;
        float wz = wave_sum(pzB) + wsfB.z;
        float ww = wave_sum(pwB) + wsfB.w;
        hs[wIdx][256 + lane]       = eluf(a0B / wx + b1[lane]);
        hs[wIdx][256 + 64 + lane]  = eluf(a1B / wy + b1[64 + lane]);
        hs[wIdx][256 + 128 + lane] = eluf(a2B / wz + b1[128 + lane]);
        hs[wIdx][256 + 192 + lane] = eluf(a3B / ww + b1[192 + lane]);
    }
    // drain this wave's hs writes; reads below are same-wave (LDS broadcast)
    asm volatile("s_waitcnt lgkmcnt(0)" ::: "memory");
    {
        float accA = 0.f, accB = 0.f;
        const float* w2l = W2 + lane;
        #pragma unroll 2
        for (int k4 = 0; k4 < 64; k4++) {
            float u0 = w2l[(size_t)(k4 * 4 + 0) * 64];
            float u1 = w2l[(size_t)(k4 * 4 + 1) * 64];
            float u2 = w2l[(size_t)(k4 * 4 + 2) * 64];
            float u3 = w2l[(size_t)(k4 * 4 + 3) * 64];
            float4 hA = *(const float4*)(&hs[wIdx][k4 * 4]);
            accA += hA.x * u0 + hA.y * u1 + hA.z * u2 + hA.w * u3;
            if (hasB) {
                float4 hB = *(const float4*)(&hs[wIdx][256 + k4 * 4]);
                accB += hB.x * u0 + hB.y * u1 + hB.z * u2 + hB.w * u3;
            }
        }
        xw2b[(size_t)nA * 64 + lane] = f2bf(accA);
        float slA = wave_sum(accA * as2[lane]);
        float srA = wave_sum(accA * ad2[lane]);
        if (lane == 0) { al2[nA] = slA; ar2[nA] = srA; }
        if (hasB) {
            xw2b[(size_t)nB * 64 + lane] = f2bf(accB);
            float slB = wave_sum(accB * as2[lane]);
            float srB = wave_sum(accB * ad2[lane]);
            if (lane == 0) { al2[nB] = slB; ar2[nB] = srB; }
        }
    }
}

// ------- layer-2 aggregate: two-phase, 8-deep gather, bf16 rows (R7-proven) -----
// R8/R10 wide-load variant was 12-16us SLOWER (2 loads in flight vs 8, serial
// acc chains) - reverted to the one-edge-per-load structure.
__global__ __launch_bounds__(256, 8) void k_agg2(const int* __restrict__ rp,
                                                 const int* __restrict__ csr,
                                                 const float* __restrict__ al2,
                                                 const float* __restrict__ ar2,
                                                 const ushort_t* __restrict__ xw2b,
                                                 const float* __restrict__ b2,
                                                 float* __restrict__ hout, int N) {
    __shared__ float wbuf[4][CH];
    __shared__ int sbuf[4][CH];
    int wIdx = threadIdx.x >> 6;
    int n = (blockIdx.x * 256 + threadIdx.x) >> 6;
    int lane = threadIdx.x & 63;
    if (n >= N) return;
    int e0 = rp[n], e1 = rp[n + 1];
    float arn = ar2[n];
    float wself = __expf(lrelu(al2[n] + arn));
    float acc = wself * bf2f(xw2b[(size_t)n * 64 + lane]);
    float p = 0.f;
    for (int cs = e0; cs < e1; cs += CH) {
        int cnt = min(CH, e1 - cs);
        if (lane < cnt) {
            int s = csr[cs + lane];
            float w = __expf(lrelu(al2[s] + arn));
            sbuf[wIdx][lane] = s;
            wbuf[wIdx][lane] = w;
            p += w;
        }
        asm volatile("s_waitcnt lgkmcnt(0)" ::: "memory");
        int jj = 0;
        for (; jj + 8 <= cnt; jj += 8) {
            int s0 = sbuf[wIdx][jj],     s1 = sbuf[wIdx][jj + 1];
            int s2 = sbuf[wIdx][jj + 2], s3 = sbuf[wIdx][jj + 3];
            int s4 = sbuf[wIdx][jj + 4], s5 = sbuf[wIdx][jj + 5];
            int s6 = sbuf[wIdx][jj + 6], s7 = sbuf[wIdx][jj + 7];
            float w0 = wbuf[wIdx][jj],     w1 = wbuf[wIdx][jj + 1];
            float w2 = wbuf[wIdx][jj + 2], w3 = wbuf[wIdx][jj + 3];
            float w4 = wbuf[wIdx][jj + 4], w5 = wbuf[wIdx][jj + 5];
            float w6 = wbuf[wIdx][jj + 6], w7 = wbuf[wIdx][jj + 7];
            float v0 = bf2f(xw2b[(size_t)s0 * 64 + lane]);
            float v1 = bf2f(xw2b[(size_t)s1 * 64 + lane]);
            float v2 = bf2f(xw2b[(size_t)s2 * 64 + lane]);
            float v3 = bf2f(xw2b[(size_t)s3 * 64 + lane]);
            float v4 = bf2f(xw2b[(size_t)s4 * 64 + lane]);
            float v5 = bf2f(xw2b[(size_t)s5 * 64 + lane]);
            float v6 = bf2f(xw2b[(size_t)s6 * 64 + lane]);
            float v7 = bf2f(xw2b[(size_t)s7 * 64 + lane]);
            acc += w0 * v0 + w1 * v1 + w2 * v2 + w3 * v3;
            acc += w4 * v4 + w5 * v5 + w6 * v6 + w7 * v7;
        }
        for (; jj + 4 <= cnt; jj += 4) {
            int s0 = sbuf[wIdx][jj],     s1 = sbuf[wIdx][jj + 1];
            int s2 = sbuf[wIdx][jj + 2], s3 = sbuf[wIdx][jj + 3];
            float w0 = wbuf[wIdx][jj],     w1 = wbuf[wIdx][jj + 1];
            float w2 = wbuf[wIdx][jj + 2], w3 = wbuf[wIdx][jj + 3];
            float v0 = bf2f(xw2b[(size_t)s0 * 64 + lane]);
            float v1 = bf2f(xw2b[(size_t)s1 * 64 + lane]);
            float v2 = bf2f(xw2b[(size_t)s2 * 64 + lane]);
            float v3 = bf2f(xw2b[(size_t)s3 * 64 + lane]);
            acc += w0 * v0 + w1 * v1 + w2 * v2 + w3 * v3;
        }
        for (; jj < cnt; jj++) {
            int s = sbuf[wIdx][jj];
            acc += wbuf[wIdx][jj] * bf2f(xw2b[(size_t)s * 64 + lane]);
        }
    }
    float wsum = wave_sum(p) + wself;
    hout[(size_t)n * 64 + lane] = eluf(acc / wsum + b2[lane]);
}

// ------- mean pool (batch sorted, 32 nodes/wave) + logits -----------------------
__global__ __launch_bounds__(256) void k_pool(const float* __restrict__ h2,
                                              const int* __restrict__ batch,
                                              float* __restrict__ pooled,
                                              float* __restrict__ cnt, int N) {
    int wave = (blockIdx.x * 256 + threadIdx.x) >> 6;
    int lane = threadIdx.x & 63;
    int n0 = wave * 32;
    if (n0 >= N) return;
    int n1 = min(n0 + 32, N);
    float acc = 0.f; int cl = 0;
    int curg = batch[n0];
    for (int n = n0; n < n1; n++) {
        int g = batch[n];
        if (g != curg) {
            atomicAdd(&pooled[curg * 64 + lane], acc);
            if (lane == 0) atomicAdd(&cnt[curg], (float)cl);
            acc = 0.f; cl = 0; curg = g;
        }
        acc += h2[(size_t)n * 64 + lane];
        cl++;
    }
    atomicAdd(&pooled[curg * 64 + lane], acc);
    if (lane == 0) atomicAdd(&cnt[curg], (float)cl);
}

__global__ __launch_bounds__(64) void k_logits(const float* __restrict__ pooled,
                                               const float* __restrict__ cnt,
                                               const float* __restrict__ fcW,
                                               const float* __restrict__ fcb,
                                               float* __restrict__ out) {
    int t = threadIdx.x;
    if (t >= NG * 2) return;
    int g = t >> 1, o = t & 1;
    float invc = 1.f / fmaxf(cnt[g], 1.f);
    float s = 0.f;
    for (int c = 0; c < 64; c++)
        s += pooled[g * 64 + c] * invc * fcW[c * 2 + o];
    s += fcb[o];
    out[g * 2 + o] = s;
}

extern "C" void kernel_launch(void* const* d_in, const int* in_sizes, int n_in,
                              void* d_out, int out_size, void* d_ws, size_t ws_size,
                              hipStream_t stream) {
    const float* x     = (const float*)d_in[0];
    const int*   ei    = (const int*)d_in[1];
    const int*   batch = (const int*)d_in[2];
    const float* W1    = (const float*)d_in[3];
    const float* as1   = (const float*)d_in[4];
    const float* ad1   = (const float*)d_in[5];
    const float* b1    = (const float*)d_in[6];
    const float* W2    = (const float*)d_in[7];
    const float* as2   = (const float*)d_in[8];
    const float* ad2   = (const float*)d_in[9];
    const float* b2v   = (const float*)d_in[10];
    const float* fcW   = (const float*)d_in[11];
    const float* fcb   = (const float*)d_in[12];
    float* out = (float*)d_out;

    const int N = in_sizes[2];       // 50000
    const int E = in_sizes[1] / 2;   // 800000
    const size_t nv  = (size_t)N * 64;
    const size_t nv4 = (size_t)N * 256;
    const int SB = (N + 1023) / 1024;

    // workspace layout: bf16 xw1, bf16 xw2, then floats, then ints (~36 MB)
    ushort_t* xw1b = (ushort_t*)d_ws;                      // nv4 ushorts (25.6 MB)
    ushort_t* xw2b   = xw1b + nv4;                         // nv ushorts (6.4 MB)
    float*    al4    = (float*)(xw2b + nv);                // N*4
    float*    ar4    = al4 + (size_t)N * 4;                // N*4
    float*    al2    = ar4 + (size_t)N * 4;                // N
    float*    ar2    = al2 + N;                            // N
    float*    pooled = ar2 + N;                            // 512
    float*    cnt    = pooled + NG * 64;                   // 8
    int*      deg    = (int*)(cnt + 8);                    // N
    int*      rp     = deg + N;                            // N+1
    int*      cur    = rp + N + 1;                         // N
    int*      csr    = cur + N;                            // E
    int*      bsum   = csr + E;                            // SB
    int*      boff   = bsum + 64;                          // SB
    // W1 in fragment order, bf16 hi/lo, 256-B aligned
    ushort_t* w1th = (ushort_t*)(((uintptr_t)(boff + 64) + 255) & ~(uintptr_t)255);
    ushort_t* w1tl = w1th + 65536;                         // 128 KB each

    const int gE  = (E + 255) / 256;
    const int gB4 = (N + 7) / 8;     // 2 nodes per wave, 8 per block
    const int gB2 = (N + 3) / 4;
    const int gG1 = (N + 31) / 32;   // 32 rows per block
    const int pw  = (N + 31) / 32;
    const int gP  = (pw * 64 + 255) / 256;

    // ---- CSR build + weight prep ----
    hipMemsetAsync(deg, 0, (size_t)N * sizeof(int), stream);
    k_hist<<<gE, 256, 0, stream>>>(ei, deg, E);
    k_scanA<<<SB, 256, 0, stream>>>(deg, bsum, N);
    k_scanB<<<1, 64, 0, stream>>>(bsum, boff, rp + N, SB);
    k_scanC<<<SB, 256, 0, stream>>>(deg, boff, rp, cur, N);
    k_fill<<<gE, 256, 0, stream>>>(ei, cur, csr, E);
    k_w1t<<<128, 256, 0, stream>>>(W1, w1th, w1tl);

    // ---- layer 1 ----
    k_gemm1<<<gG1, 256, 0, stream>>>(x, w1th, w1tl, as1, ad1, xw1b, al4, ar4, N);
    k_agg4<<<gB4, 256, 0, stream>>>(rp, csr, al4, ar4, xw1b, b1, W2, as2, ad2,
                                    xw2b, al2, ar2, N);

    // ---- layer 2 ----
    k_agg2<<<gB2, 256, 0, stream>>>(rp, csr, al2, ar2, xw2b, b2v, out, N);

    // ---- pooling + logits ----
    hipMemsetAsync(pooled, 0, (NG * 64 + NG) * sizeof(float), stream);
    k_pool<<<gP, 256, 0, stream>>>(out, batch, pooled, cnt, N);
    k_logits<<<1, 64, 0, stream>>>(pooled, cnt, fcW, fcb, out + nv);
}

// Round 12
// 453.879 us; speedup vs baseline: 1.1004x; 1.1004x over previous
//
#include <hip/hip_runtime.h>

#define NEG_SLOPE 0.2f
#define NG 8
#define CH 64   // edge chunk per wave (lane-parallel weight phase)

typedef unsigned short ushort_t;
typedef __attribute__((ext_vector_type(8))) short short8v;   // 8 bf16 (4 VGPRs)
typedef __attribute__((ext_vector_type(4))) float f32x4;     // MFMA C/D frag

__device__ __forceinline__ float lrelu(float x) { return x > 0.f ? x : NEG_SLOPE * x; }
__device__ __forceinline__ float eluf(float x) { return x > 0.f ? x : expm1f(x); }
__device__ __forceinline__ float wave_sum(float v) {
    #pragma unroll
    for (int o = 32; o; o >>= 1) v += __shfl_xor(v, o);
    return v;
}
// f32 <-> bf16 (RNE), finite inputs only
__device__ __forceinline__ ushort_t f2bf(float f) {
    unsigned u = __float_as_uint(f);
    unsigned r = (u + 0x7FFFu + ((u >> 16) & 1u)) >> 16;
    return (ushort_t)r;
}
__device__ __forceinline__ float bf2f(ushort_t s) {
    return __uint_as_float(((unsigned)s) << 16);
}

// ---------------- CSR build ----------------------------------------------------
__global__ __launch_bounds__(256) void k_hist(const int* __restrict__ ei,
                                              int* __restrict__ deg, int E) {
    int e = blockIdx.x * 256 + threadIdx.x;
    if (e < E) atomicAdd(&deg[ei[E + e]], 1);
}

__global__ __launch_bounds__(256) void k_scanA(const int* __restrict__ deg,
                                               int* __restrict__ bsum, int N) {
    __shared__ int wsums[4];
    int b = blockIdx.x, t = threadIdx.x;
    int base = b * 1024 + t * 4;
    int s = 0;
    #pragma unroll
    for (int k = 0; k < 4; k++) { int i = base + k; if (i < N) s += deg[i]; }
    #pragma unroll
    for (int o = 32; o; o >>= 1) s += __shfl_xor(s, o);
    if ((t & 63) == 0) wsums[t >> 6] = s;
    __syncthreads();
    if (t == 0) bsum[b] = wsums[0] + wsums[1] + wsums[2] + wsums[3];
}

__global__ __launch_bounds__(64) void k_scanB(const int* __restrict__ bsum,
                                              int* __restrict__ boff,
                                              int* __restrict__ rpN, int SB) {
    int lane = threadIdx.x;
    int own = (lane < SB) ? bsum[lane] : 0;
    int v = own;
    #pragma unroll
    for (int o = 1; o < 64; o <<= 1) { int y = __shfl_up(v, o); if (lane >= o) v += y; }
    if (lane < SB) boff[lane] = v - own;
    if (lane == 63) *rpN = v;
}

__global__ __launch_bounds__(256) void k_scanC(const int* __restrict__ deg,
                                               const int* __restrict__ boff,
                                               int* __restrict__ rp,
                                               int* __restrict__ cur, int N) {
    __shared__ int wtot[4];
    int b = blockIdx.x, t = threadIdx.x;
    int wid = t >> 6, lane = t & 63;
    int base = b * 1024 + t * 4;
    int d[4];
    #pragma unroll
    for (int k = 0; k < 4; k++) d[k] = (base + k < N) ? deg[base + k] : 0;
    int tsum = d[0] + d[1] + d[2] + d[3];
    int v = tsum;
    #pragma unroll
    for (int o = 1; o < 64; o <<= 1) { int y = __shfl_up(v, o); if (lane >= o) v += y; }
    if (lane == 63) wtot[wid] = v;
    __syncthreads();
    int wbase = 0;
    for (int k = 0; k < wid; k++) wbase += wtot[k];
    int run = boff[b] + wbase + v - tsum;
    #pragma unroll
    for (int k = 0; k < 4; k++) {
        if (base + k < N) { rp[base + k] = run; cur[base + k] = run; }
        run += d[k];
    }
}

__global__ __launch_bounds__(256) void k_fill(const int* __restrict__ ei,
                                              int* __restrict__ cur,
                                              int* __restrict__ csr, int E) {
    int e = blockIdx.x * 256 + threadIdx.x;
    if (e >= E) return;
    int s = ei[e], d = ei[E + e];
    int pos = atomicAdd(&cur[d], 1);
    csr[pos] = s;
}

// ------- W1 -> bf16 hi/lo in MFMA-fragment order --------------------------------
__global__ __launch_bounds__(256) void k_w1t(const float* __restrict__ W1,
                                             ushort_t* __restrict__ w1th,
                                             ushort_t* __restrict__ w1tl) {
    int tile = blockIdx.x >> 3, ks = blockIdx.x & 7;   // 128 blocks
    for (int i = threadIdx.x; i < 512; i += 256) {
        int lane = i >> 3, e = i & 7;
        int jl = lane & 15, q = lane >> 4;
        int col = tile * 16 + jl;
        int k = ks * 32 + 8 * q + e;
        float w = W1[(size_t)k * 256 + col];
        ushort_t hi = f2bf(w);
        float lo = w - bf2f(hi);
        size_t o = (size_t)blockIdx.x * 512 + i;
        w1th[o] = hi;
        w1tl[o] = f2bf(lo);
    }
}

// ------- GEMM1 via split-bf16 MFMA (R7-proven): xw1 = x @ W1 + al/ar epilogue ---
__global__ __launch_bounds__(256, 4) void k_gemm1(const float* __restrict__ x,
                                               const ushort_t* __restrict__ w1th,
                                               const ushort_t* __restrict__ w1tl,
                                               const float* __restrict__ a_s,
                                               const float* __restrict__ a_d,
                                               ushort_t* __restrict__ xw1b,
                                               float* __restrict__ al4,
                                               float* __restrict__ ar4, int N) {
    __shared__ __align__(16) unsigned char smem[33792];
    ushort_t* xh = (ushort_t*)smem;
    ushort_t* xl = (ushort_t*)(smem + 16896);
    int r0 = blockIdx.x * 32;
    int tid = threadIdx.x;
    int lane = tid & 63, wv = tid >> 6;
    // ---- stage x -> bf16 hi/lo in LDS ----
    for (int i = tid; i < 2048; i += 256) {
        int r = i >> 6, k4 = (i & 63) << 2;
        float4 v = (r0 + r < N) ? *(const float4*)(x + (size_t)(r0 + r) * 256 + k4)
                                : make_float4(0.f, 0.f, 0.f, 0.f);
        ushort4 h4, l4;
        h4.x = f2bf(v.x); l4.x = f2bf(v.x - bf2f(h4.x));
        h4.y = f2bf(v.y); l4.y = f2bf(v.y - bf2f(h4.y));
        h4.z = f2bf(v.z); l4.z = f2bf(v.z - bf2f(h4.z));
        h4.w = f2bf(v.w); l4.w = f2bf(v.w - bf2f(h4.w));
        *(ushort4*)(&xh[r * 264 + k4]) = h4;
        *(ushort4*)(&xl[r * 264 + k4]) = l4;
    }
    __syncthreads();
    // ---- MFMA K-loop ----
    int wr = wv & 1, wc = wv >> 1;       // 2x2 wave grid
    int jl = lane & 15, q = lane >> 4;
    f32x4 acc[8];
    #pragma unroll
    for (int t = 0; t < 8; t++) acc[t] = (f32x4){0.f, 0.f, 0.f, 0.f};
    const ushort_t* xhp = &xh[(16 * wr + jl) * 264];
    const ushort_t* xlp = &xl[(16 * wr + jl) * 264];
    const ushort_t* bhb = w1th + (size_t)wc * 32768 + lane * 8;
    const ushort_t* blb = w1tl + (size_t)wc * 32768 + lane * 8;
    #pragma unroll 1
    for (int ks = 0; ks < 8; ks++) {
        int ko = 32 * ks + 8 * q;
        short8v ah = *(const short8v*)(xhp + ko);
        short8v alo = *(const short8v*)(xlp + ko);
        #pragma unroll
        for (int tp = 0; tp < 4; tp++) {
            int t0 = 2 * tp, t1 = 2 * tp + 1;
            short8v bh0 = *(const short8v*)(bhb + (t0 * 8 + ks) * 512);
            short8v bl0 = *(const short8v*)(blb + (t0 * 8 + ks) * 512);
            short8v bh1 = *(const short8v*)(bhb + (t1 * 8 + ks) * 512);
            short8v bl1 = *(const short8v*)(blb + (t1 * 8 + ks) * 512);
            acc[t0] = __builtin_amdgcn_mfma_f32_16x16x32_bf16(ah, bh0, acc[t0], 0, 0, 0);
            acc[t0] = __builtin_amdgcn_mfma_f32_16x16x32_bf16(ah, bl0, acc[t0], 0, 0, 0);
            acc[t0] = __builtin_amdgcn_mfma_f32_16x16x32_bf16(alo, bh0, acc[t0], 0, 0, 0);
            acc[t1] = __builtin_amdgcn_mfma_f32_16x16x32_bf16(ah, bh1, acc[t1], 0, 0, 0);
            acc[t1] = __builtin_amdgcn_mfma_f32_16x16x32_bf16(ah, bl1, acc[t1], 0, 0, 0);
            acc[t1] = __builtin_amdgcn_mfma_f32_16x16x32_bf16(alo, bh1, acc[t1], 0, 0, 0);
        }
    }
    __syncthreads();                     // everyone done reading xh/xl
    // ---- D frags -> LDS f32 [32][256] ----
    float* outb = (float*)smem;
    #pragma unroll
    for (int t = 0; t < 8; t++) {
        int c = 128 * wc + 16 * t + jl;
        int rb = 16 * wr + 4 * q;
        outb[(rb + 0) * 256 + c] = acc[t].x;
        outb[(rb + 1) * 256 + c] = acc[t].y;
        outb[(rb + 2) * 256 + c] = acc[t].z;
        outb[(rb + 3) * 256 + c] = acc[t].w;
    }
    __syncthreads();
    // ---- epilogue (proven structure): al/ar + bf16 repack + coalesced store ----
    int c4 = lane << 2;
    int h = lane >> 4, kk = c4 & 63;
    float4 s4 = *(const float4*)(a_s + h * 64 + kk);
    float4 d4 = *(const float4*)(a_d + h * 64 + kk);
    float4 hv[8];
    #pragma unroll
    for (int t2 = 0; t2 < 8; t2++)
        hv[t2] = *(const float4*)(&outb[(wv + 4 * t2) * 256 + c4]);
    #pragma unroll
    for (int t2 = 0; t2 < 8; t2++) {
        float sl = hv[t2].x * s4.x + hv[t2].y * s4.y + hv[t2].z * s4.z + hv[t2].w * s4.w;
        float sr = hv[t2].x * d4.x + hv[t2].y * d4.y + hv[t2].z * d4.z + hv[t2].w * d4.w;
        #pragma unroll
        for (int o = 1; o < 16; o <<= 1) { sl += __shfl_xor(sl, o); sr += __shfl_xor(sr, o); }
        int r = r0 + wv + 4 * t2;
        if ((lane & 15) == 0 && r < N) {
            al4[(size_t)r * 4 + h] = sl;
            ar4[(size_t)r * 4 + h] = sr;
        }
    }
    __syncthreads();                     // all reads of outb complete
    ushort_t* Ls = (ushort_t*)smem;      // [32][256]
    #pragma unroll
    for (int t2 = 0; t2 < 8; t2++) {
        int rl = wv + 4 * t2;
        Ls[rl * 256 + (kk + 0) * 4 + h] = f2bf(hv[t2].x);
        Ls[rl * 256 + (kk + 1) * 4 + h] = f2bf(hv[t2].y);
        Ls[rl * 256 + (kk + 2) * 4 + h] = f2bf(hv[t2].z);
        Ls[rl * 256 + (kk + 3) * 4 + h] = f2bf(hv[t2].w);
    }
    __syncthreads();
    #pragma unroll
    for (int p = 0; p < 4; p++) {
        int flat = p * 2048 + tid * 8;   // 8 ushorts = 16 B per thread
        int rl = flat >> 8, col = flat & 255;
        int r = r0 + rl;
        if (r < N)
            *(uint4*)(xw1b + (size_t)r * 256 + col) = *(const uint4*)(Ls + flat);
    }
}

__device__ __forceinline__ float4 wexp4(float4 a, float4 arn) {
    float4 w;
    w.x = __expf(lrelu(a.x + arn.x));
    w.y = __expf(lrelu(a.y + arn.y));
    w.z = __expf(lrelu(a.z + arn.z));
    w.w = __expf(lrelu(a.w + arn.w));
    return w;
}

// gather one node's layer-1 aggregation into hrow[0..255] (R7-proven, BYTE-IDENTICAL;
// every structural variation -- deeper in-flight, wide loads, split phases,
// reference params -- spilled to scratch (R2/R8/R11). Do not modify.)
__device__ __forceinline__ void gather1(int n, int lane,
                                        const int* __restrict__ rp,
                                        const int* __restrict__ csr,
                                        const float* __restrict__ al4,
                                        const float* __restrict__ ar4,
                                        const ushort_t* __restrict__ xw1b,
                                        const float* __restrict__ b1,
                                        float4* __restrict__ wb,
                                        int* __restrict__ sb,
                                        float* __restrict__ hrow) {
    int e0 = rp[n], e1 = rp[n + 1];
    float4 arn = *(const float4*)(ar4 + (size_t)n * 4);
    float4 aln = *(const float4*)(al4 + (size_t)n * 4);
    float4 wsf = wexp4(aln, arn);           // self-loop weight
    ushort4 sv = *(const ushort4*)(xw1b + (size_t)n * 256 + lane * 4);
    float a0 = wsf.x * bf2f(sv.x);
    float a1 = wsf.y * bf2f(sv.y);
    float a2 = wsf.z * bf2f(sv.z);
    float a3 = wsf.w * bf2f(sv.w);
    float px = 0.f, py = 0.f, pz = 0.f, pw = 0.f;   // lane-partial weight sums
    for (int cs = e0; cs < e1; cs += CH) {
        int cnt = min(CH, e1 - cs);
        if (lane < cnt) {
            int s = csr[cs + lane];
            float4 A = *(const float4*)(al4 + (size_t)s * 4);
            float4 w = wexp4(A, arn);
            sb[lane] = s;
            wb[lane] = w;
            px += w.x; py += w.y; pz += w.z; pw += w.w;
        }
        // drain LDS writes; per-wave LDS is in-order, no block barrier needed
        asm volatile("s_waitcnt lgkmcnt(0)" ::: "memory");
        int jj = 0;
        for (; jj + 4 <= cnt; jj += 4) {
            int s0 = sb[jj],     s1 = sb[jj + 1];
            int s2 = sb[jj + 2], s3 = sb[jj + 3];
            float4 w0 = wb[jj],     w1 = wb[jj + 1];
            float4 w2 = wb[jj + 2], w3 = wb[jj + 3];
            ushort4 v0 = *(const ushort4*)(xw1b + (size_t)s0 * 256 + lane * 4);
            ushort4 v1 = *(const ushort4*)(xw1b + (size_t)s1 * 256 + lane * 4);
            ushort4 v2 = *(const ushort4*)(xw1b + (size_t)s2 * 256 + lane * 4);
            ushort4 v3 = *(const ushort4*)(xw1b + (size_t)s3 * 256 + lane * 4);
            a0 += w0.x * bf2f(v0.x) + w1.x * bf2f(v1.x) + w2.x * bf2f(v2.x) + w3.x * bf2f(v3.x);
            a1 += w0.y * bf2f(v0.y) + w1.y * bf2f(v1.y) + w2.y * bf2f(v2.y) + w3.y * bf2f(v3.y);
            a2 += w0.z * bf2f(v0.z) + w1.z * bf2f(v1.z) + w2.z * bf2f(v2.z) + w3.z * bf2f(v3.z);
            a3 += w0.w * bf2f(v0.w) + w1.w * bf2f(v1.w) + w2.w * bf2f(v2.w) + w3.w * bf2f(v3.w);
        }
        for (; jj < cnt; jj++) {
            int s = sb[jj];
            float4 w = wb[jj];
            ushort4 v = *(const ushort4*)(xw1b + (size_t)s * 256 + lane * 4);
            a0 += w.x * bf2f(v.x);
            a1 += w.y * bf2f(v.y);
            a2 += w.z * bf2f(v.z);
            a3 += w.w * bf2f(v.w);
        }
    }
    float wx = wave_sum(px) + wsf.x;
    float wy = wave_sum(py) + wsf.y;
    float wz = wave_sum(pz) + wsf.z;
    float ww = wave_sum(pw) + wsf.w;
    hrow[lane]       = eluf(a0 / wx + b1[lane]);
    hrow[64 + lane]  = eluf(a1 / wy + b1[64 + lane]);
    hrow[128 + lane] = eluf(a2 / wz + b1[128 + lane]);
    hrow[192 + lane] = eluf(a3 / ww + b1[192 + lane]);
}

// ------- layer-1 aggregate: 4 nodes per wave, shared-W2 phase 2 -----------------
// R12: extends the R4-proven W2-share (2 nodes: -13us) to 4 nodes -- phase-2 W2
// traffic 1.6 -> 0.8 GB, 16 FMA per 4 W2 loads. gather1 untouched (R7 shape).
__global__ __launch_bounds__(256, 8) void k_agg4(const int* __restrict__ rp,
                                                 const int* __restrict__ csr,
                                                 const float* __restrict__ al4,
                                                 const float* __restrict__ ar4,
                                                 const ushort_t* __restrict__ xw1b,
                                                 const float* __restrict__ b1,
                                                 const float* __restrict__ W2,
                                                 const float* __restrict__ as2,
                                                 const float* __restrict__ ad2,
                                                 ushort_t* __restrict__ xw2b,
                                                 float* __restrict__ al2,
                                                 float* __restrict__ ar2, int N) {
    __shared__ float hs[4][1024];       // 4 nodes x 256 per wave (16 KB)
    __shared__ float4 wbuf[4][CH];      // shared across sequential gathers
    __shared__ int sbuf[4][CH];
    int wIdx = threadIdx.x >> 6;
    int w = (blockIdx.x * 256 + threadIdx.x) >> 6;
    int lane = threadIdx.x & 63;
    int n0 = 4 * w;
    if (n0 >= N) return;
    #pragma unroll 1
    for (int j = 0; j < 4; j++) {
        int n = n0 + j;
        if (n < N)
            gather1(n, lane, rp, csr, al4, ar4, xw1b, b1, wbuf[wIdx], sbuf[wIdx],
                    &hs[wIdx][256 * j]);
    }
    // drain this wave's hs writes; reads below are same-wave (LDS broadcast)
    asm volatile("s_waitcnt lgkmcnt(0)" ::: "memory");
    {
        bool h1 = (n0 + 1 < N), h2 = (n0 + 2 < N), h3 = (n0 + 3 < N);
        float acc0 = 0.f, acc1 = 0.f, acc2 = 0.f, acc3 = 0.f;
        const float* w2l = W2 + lane;
        #pragma unroll 2
        for (int k4 = 0; k4 < 64; k4++) {
            float u0 = w2l[(size_t)(k4 * 4 + 0) * 64];
            float u1 = w2l[(size_t)(k4 * 4 + 1) * 64];
            float u2 = w2l[(size_t)(k4 * 4 + 2) * 64];
            float u3 = w2l[(size_t)(k4 * 4 + 3) * 64];
            float4 hA = *(const float4*)(&hs[wIdx][k4 * 4]);
            acc0 += hA.x * u0 + hA.y * u1 + hA.z * u2 + hA.w * u3;
            if (h1) {
                float4 hB = *(const float4*)(&hs[wIdx][256 + k4 * 4]);
                acc1 += hB.x * u0 + hB.y * u1 + hB.z * u2 + hB.w * u3;
            }
            if (h2) {
                float4 hC = *(const float4*)(&hs[wIdx][512 + k4 * 4]);
                acc2 += hC.x * u0 + hC.y * u1 + hC.z * u2 + hC.w * u3;
            }
            if (h3) {
                float4 hD = *(const float4*)(&hs[wIdx][768 + k4 * 4]);
                acc3 += hD.x * u0 + hD.y * u1 + hD.z * u2 + hD.w * u3;
            }
        }
        xw2b[(size_t)n0 * 64 + lane] = f2bf(acc0);
        float sl = wave_sum(acc0 * as2[lane]);
        float sr = wave_sum(acc0 * ad2[lane]);
        if (lane == 0) { al2[n0] = sl; ar2[n0] = sr; }
        if (h1) {
            xw2b[(size_t)(n0 + 1) * 64 + lane] = f2bf(acc1);
            float sl1 = wave_sum(acc1 * as2[lane]);
            float sr1 = wave_sum(acc1 * ad2[lane]);
            if (lane == 0) { al2[n0 + 1] = sl1; ar2[n0 + 1] = sr1; }
        }
        if (h2) {
            xw2b[(size_t)(n0 + 2) * 64 + lane] = f2bf(acc2);
            float sl2 = wave_sum(acc2 * as2[lane]);
            float sr2 = wave_sum(acc2 * ad2[lane]);
            if (lane == 0) { al2[n0 + 2] = sl2; ar2[n0 + 2] = sr2; }
        }
        if (h3) {
            xw2b[(size_t)(n0 + 3) * 64 + lane] = f2bf(acc3);
            float sl3 = wave_sum(acc3 * as2[lane]);
            float sr3 = wave_sum(acc3 * ad2[lane]);
            if (lane == 0) { al2[n0 + 3] = sl3; ar2[n0 + 3] = sr3; }
        }
    }
}

// ------- layer-2 aggregate: two-phase, 8-deep gather, bf16 rows (R7-proven) -----
__global__ __launch_bounds__(256, 8) void k_agg2(const int* __restrict__ rp,
                                                 const int* __restrict__ csr,
                                                 const float* __restrict__ al2,
                                                 const float* __restrict__ ar2,
                                                 const ushort_t* __restrict__ xw2b,
                                                 const float* __restrict__ b2,
                                                 float* __restrict__ hout, int N) {
    __shared__ float wbuf[4][CH];
    __shared__ int sbuf[4][CH];
    int wIdx = threadIdx.x >> 6;
    int n = (blockIdx.x * 256 + threadIdx.x) >> 6;
    int lane = threadIdx.x & 63;
    if (n >= N) return;
    int e0 = rp[n], e1 = rp[n + 1];
    float arn = ar2[n];
    float wself = __expf(lrelu(al2[n] + arn));
    float acc = wself * bf2f(xw2b[(size_t)n * 64 + lane]);
    float p = 0.f;
    for (int cs = e0; cs < e1; cs += CH) {
        int cnt = min(CH, e1 - cs);
        if (lane < cnt) {
            int s = csr[cs + lane];
            float w = __expf(lrelu(al2[s] + arn));
            sbuf[wIdx][lane] = s;
            wbuf[wIdx][lane] = w;
            p += w;
        }
        asm volatile("s_waitcnt lgkmcnt(0)" ::: "memory");
        int jj = 0;
        for (; jj + 8 <= cnt; jj += 8) {
            int s0 = sbuf[wIdx][jj],     s1 = sbuf[wIdx][jj + 1];
            int s2 = sbuf[wIdx][jj + 2], s3 = sbuf[wIdx][jj + 3];
            int s4 = sbuf[wIdx][jj + 4], s5 = sbuf[wIdx][jj + 5];
            int s6 = sbuf[wIdx][jj + 6], s7 = sbuf[wIdx][jj + 7];
            float w0 = wbuf[wIdx][jj],     w1 = wbuf[wIdx][jj + 1];
            float w2 = wbuf[wIdx][jj + 2], w3 = wbuf[wIdx][jj + 3];
            float w4 = wbuf[wIdx][jj + 4], w5 = wbuf[wIdx][jj + 5];
            float w6 = wbuf[wIdx][jj + 6], w7 = wbuf[wIdx][jj + 7];
            float v0 = bf2f(xw2b[(size_t)s0 * 64 + lane]);
            float v1 = bf2f(xw2b[(size_t)s1 * 64 + lane]);
            float v2 = bf2f(xw2b[(size_t)s2 * 64 + lane]);
            float v3 = bf2f(xw2b[(size_t)s3 * 64 + lane]);
            float v4 = bf2f(xw2b[(size_t)s4 * 64 + lane]);
            float v5 = bf2f(xw2b[(size_t)s5 * 64 + lane]);
            float v6 = bf2f(xw2b[(size_t)s6 * 64 + lane]);
            float v7 = bf2f(xw2b[(size_t)s7 * 64 + lane]);
            acc += w0 * v0 + w1 * v1 + w2 * v2 + w3 * v3;
            acc += w4 * v4 + w5 * v5 + w6 * v6 + w7 * v7;
        }
        for (; jj + 4 <= cnt; jj += 4) {
            int s0 = sbuf[wIdx][jj],     s1 = sbuf[wIdx][jj + 1];
            int s2 = sbuf[wIdx][jj + 2], s3 = sbuf[wIdx][jj + 3];
            float w0 = wbuf[wIdx][jj],     w1 = wbuf[wIdx][jj + 1];
            float w2 = wbuf[wIdx][jj + 2], w3 = wbuf[wIdx][jj + 3];
            float v0 = bf2f(xw2b[(size_t)s0 * 64 + lane]);
            float v1 = bf2f(xw2b[(size_t)s1 * 64 + lane]);
            float v2 = bf2f(xw2b[(size_t)s2 * 64 + lane]);
            float v3 = bf2f(xw2b[(size_t)s3 * 64 + lane]);
            acc += w0 * v0 + w1 * v1 + w2 * v2 + w3 * v3;
        }
        for (; jj < cnt; jj++) {
            int s = sbuf[wIdx][jj];
            acc += wbuf[wIdx][jj] * bf2f(xw2b[(size_t)s * 64 + lane]);
        }
    }
    float wsum = wave_sum(p) + wself;
    hout[(size_t)n * 64 + lane] = eluf(acc / wsum + b2[lane]);
}

// ------- mean pool (batch sorted, 32 nodes/wave) + logits -----------------------
__global__ __launch_bounds__(256) void k_pool(const float* __restrict__ h2,
                                              const int* __restrict__ batch,
                                              float* __restrict__ pooled,
                                              float* __restrict__ cnt, int N) {
    int wave = (blockIdx.x * 256 + threadIdx.x) >> 6;
    int lane = threadIdx.x & 63;
    int n0 = wave * 32;
    if (n0 >= N) return;
    int n1 = min(n0 + 32, N);
    float acc = 0.f; int cl = 0;
    int curg = batch[n0];
    for (int n = n0; n < n1; n++) {
        int g = batch[n];
        if (g != curg) {
            atomicAdd(&pooled[curg * 64 + lane], acc);
            if (lane == 0) atomicAdd(&cnt[curg], (float)cl);
            acc = 0.f; cl = 0; curg = g;
        }
        acc += h2[(size_t)n * 64 + lane];
        cl++;
    }
    atomicAdd(&pooled[curg * 64 + lane], acc);
    if (lane == 0) atomicAdd(&cnt[curg], (float)cl);
}

__global__ __launch_bounds__(64) void k_logits(const float* __restrict__ pooled,
                                               const float* __restrict__ cnt,
                                               const float* __restrict__ fcW,
                                               const float* __restrict__ fcb,
                                               float* __restrict__ out) {
    int t = threadIdx.x;
    if (t >= NG * 2) return;
    int g = t >> 1, o = t & 1;
    float invc = 1.f / fmaxf(cnt[g], 1.f);
    float s = 0.f;
    for (int c = 0; c < 64; c++)
        s += pooled[g * 64 + c] * invc * fcW[c * 2 + o];
    s += fcb[o];
    out[g * 2 + o] = s;
}

extern "C" void kernel_launch(void* const* d_in, const int* in_sizes, int n_in,
                              void* d_out, int out_size, void* d_ws, size_t ws_size,
                              hipStream_t stream) {
    const float* x     = (const float*)d_in[0];
    const int*   ei    = (const int*)d_in[1];
    const int*   batch = (const int*)d_in[2];
    const float* W1    = (const float*)d_in[3];
    const float* as1   = (const float*)d_in[4];
    const float* ad1   = (const float*)d_in[5];
    const float* b1    = (const float*)d_in[6];
    const float* W2    = (const float*)d_in[7];
    const float* as2   = (const float*)d_in[8];
    const float* ad2   = (const float*)d_in[9];
    const float* b2v   = (const float*)d_in[10];
    const float* fcW   = (const float*)d_in[11];
    const float* fcb   = (const float*)d_in[12];
    float* out = (float*)d_out;

    const int N = in_sizes[2];       // 50000
    const int E = in_sizes[1] / 2;   // 800000
    const size_t nv  = (size_t)N * 64;
    const size_t nv4 = (size_t)N * 256;
    const int SB = (N + 1023) / 1024;

    // workspace layout: bf16 xw1, bf16 xw2, then floats, then ints (~36 MB)
    ushort_t* xw1b = (ushort_t*)d_ws;                      // nv4 ushorts (25.6 MB)
    ushort_t* xw2b   = xw1b + nv4;                         // nv ushorts (6.4 MB)
    float*    al4    = (float*)(xw2b + nv);                // N*4
    float*    ar4    = al4 + (size_t)N * 4;                // N*4
    float*    al2    = ar4 + (size_t)N * 4;                // N
    float*    ar2    = al2 + N;                            // N
    float*    pooled = ar2 + N;                            // 512
    float*    cnt    = pooled + NG * 64;                   // 8
    int*      deg    = (int*)(cnt + 8);                    // N
    int*      rp     = deg + N;                            // N+1
    int*      cur    = rp + N + 1;                         // N
    int*      csr    = cur + N;                            // E
    int*      bsum   = csr + E;                            // SB
    int*      boff   = bsum + 64;                          // SB
    // W1 in fragment order, bf16 hi/lo, 256-B aligned
    ushort_t* w1th = (ushort_t*)(((uintptr_t)(boff + 64) + 255) & ~(uintptr_t)255);
    ushort_t* w1tl = w1th + 65536;                         // 128 KB each

    const int gE  = (E + 255) / 256;
    const int gB4 = (N + 15) / 16;   // 4 nodes per wave, 16 per block
    const int gB2 = (N + 3) / 4;
    const int gG1 = (N + 31) / 32;   // 32 rows per block
    const int pw  = (N + 31) / 32;
    const int gP  = (pw * 64 + 255) / 256;

    // ---- CSR build + weight prep ----
    hipMemsetAsync(deg, 0, (size_t)N * sizeof(int), stream);
    k_hist<<<gE, 256, 0, stream>>>(ei, deg, E);
    k_scanA<<<SB, 256, 0, stream>>>(deg, bsum, N);
    k_scanB<<<1, 64, 0, stream>>>(bsum, boff, rp + N, SB);
    k_scanC<<<SB, 256, 0, stream>>>(deg, boff, rp, cur, N);
    k_fill<<<gE, 256, 0, stream>>>(ei, cur, csr, E);
    k_w1t<<<128, 256, 0, stream>>>(W1, w1th, w1tl);

    // ---- layer 1 ----
    k_gemm1<<<gG1, 256, 0, stream>>>(x, w1th, w1tl, as1, ad1, xw1b, al4, ar4, N);
    k_agg4<<<gB4, 256, 0, stream>>>(rp, csr, al4, ar4, xw1b, b1, W2, as2, ad2,
                                    xw2b, al2, ar2, N);

    // ---- layer 2 ----
    k_agg2<<<gB2, 256, 0, stream>>>(rp, csr, al2, ar2, xw2b, b2v, out, N);

    // ---- pooling + logits ----
    hipMemsetAsync(pooled, 0, (NG * 64 + NG) * sizeof(float), stream);
    k_pool<<<gP, 256, 0, stream>>>(out, batch, pooled, cnt, N);
    k_logits<<<1, 64, 0, stream>>>(pooled, cnt, fcW, fcb, out + nv);
}

// Round 13
// 446.605 us; speedup vs baseline: 1.1183x; 1.0163x over previous
//
#include <hip/hip_runtime.h>

#define NEG_SLOPE 0.2f
#define NG 8
#define CH 64   // edge chunk per wave (lane-parallel weight phase)

typedef unsigned short ushort_t;
typedef __attribute__((ext_vector_type(8))) short short8v;   // 8 bf16 (4 VGPRs)
typedef __attribute__((ext_vector_type(4))) float f32x4;     // MFMA C/D frag

__device__ __forceinline__ float lrelu(float x) { return x > 0.f ? x : NEG_SLOPE * x; }
__device__ __forceinline__ float eluf(float x) { return x > 0.f ? x : expm1f(x); }
__device__ __forceinline__ float wave_sum(float v) {
    #pragma unroll
    for (int o = 32; o; o >>= 1) v += __shfl_xor(v, o);
    return v;
}
// f32 <-> bf16 (RNE), finite inputs only
__device__ __forceinline__ ushort_t f2bf(float f) {
    unsigned u = __float_as_uint(f);
    unsigned r = (u + 0x7FFFu + ((u >> 16) & 1u)) >> 16;
    return (ushort_t)r;
}
__device__ __forceinline__ float bf2f(ushort_t s) {
    return __uint_as_float(((unsigned)s) << 16);
}

// ---------------- CSR build ----------------------------------------------------
__global__ __launch_bounds__(256) void k_hist(const int* __restrict__ ei,
                                              int* __restrict__ deg, int E) {
    int e = blockIdx.x * 256 + threadIdx.x;
    if (e < E) atomicAdd(&deg[ei[E + e]], 1);
}

__global__ __launch_bounds__(256) void k_scanA(const int* __restrict__ deg,
                                               int* __restrict__ bsum, int N) {
    __shared__ int wsums[4];
    int b = blockIdx.x, t = threadIdx.x;
    int base = b * 1024 + t * 4;
    int s = 0;
    #pragma unroll
    for (int k = 0; k < 4; k++) { int i = base + k; if (i < N) s += deg[i]; }
    #pragma unroll
    for (int o = 32; o; o >>= 1) s += __shfl_xor(s, o);
    if ((t & 63) == 0) wsums[t >> 6] = s;
    __syncthreads();
    if (t == 0) bsum[b] = wsums[0] + wsums[1] + wsums[2] + wsums[3];
}

__global__ __launch_bounds__(64) void k_scanB(const int* __restrict__ bsum,
                                              int* __restrict__ boff,
                                              int* __restrict__ rpN, int SB) {
    int lane = threadIdx.x;
    int own = (lane < SB) ? bsum[lane] : 0;
    int v = own;
    #pragma unroll
    for (int o = 1; o < 64; o <<= 1) { int y = __shfl_up(v, o); if (lane >= o) v += y; }
    if (lane < SB) boff[lane] = v - own;
    if (lane == 63) *rpN = v;
}

__global__ __launch_bounds__(256) void k_scanC(const int* __restrict__ deg,
                                               const int* __restrict__ boff,
                                               int* __restrict__ rp,
                                               int* __restrict__ cur, int N) {
    __shared__ int wtot[4];
    int b = blockIdx.x, t = threadIdx.x;
    int wid = t >> 6, lane = t & 63;
    int base = b * 1024 + t * 4;
    int d[4];
    #pragma unroll
    for (int k = 0; k < 4; k++) d[k] = (base + k < N) ? deg[base + k] : 0;
    int tsum = d[0] + d[1] + d[2] + d[3];
    int v = tsum;
    #pragma unroll
    for (int o = 1; o < 64; o <<= 1) { int y = __shfl_up(v, o); if (lane >= o) v += y; }
    if (lane == 63) wtot[wid] = v;
    __syncthreads();
    int wbase = 0;
    for (int k = 0; k < wid; k++) wbase += wtot[k];
    int run = boff[b] + wbase + v - tsum;
    #pragma unroll
    for (int k = 0; k < 4; k++) {
        if (base + k < N) { rp[base + k] = run; cur[base + k] = run; }
        run += d[k];
    }
}

__global__ __launch_bounds__(256) void k_fill(const int* __restrict__ ei,
                                              int* __restrict__ cur,
                                              int* __restrict__ csr, int E) {
    int e = blockIdx.x * 256 + threadIdx.x;
    if (e >= E) return;
    int s = ei[e], d = ei[E + e];
    int pos = atomicAdd(&cur[d], 1);
    csr[pos] = s;
}

// ------- W1 -> bf16 hi/lo in MFMA-fragment order --------------------------------
__global__ __launch_bounds__(256) void k_w1t(const float* __restrict__ W1,
                                             ushort_t* __restrict__ w1th,
                                             ushort_t* __restrict__ w1tl) {
    int tile = blockIdx.x >> 3, ks = blockIdx.x & 7;   // 128 blocks
    for (int i = threadIdx.x; i < 512; i += 256) {
        int lane = i >> 3, e = i & 7;
        int jl = lane & 15, q = lane >> 4;
        int col = tile * 16 + jl;
        int k = ks * 32 + 8 * q + e;
        float w = W1[(size_t)k * 256 + col];
        ushort_t hi = f2bf(w);
        float lo = w - bf2f(hi);
        size_t o = (size_t)blockIdx.x * 512 + i;
        w1th[o] = hi;
        w1tl[o] = f2bf(lo);
    }
}

// ------- GEMM1 via split-bf16 MFMA: xw1 = x @ W1 + al/ar epilogue ---------------
// R13: wave tile reshaped 16x128 -> 32x64 (2 row-groups x 4 col-tiles). B frags
// reused across both row-groups in registers: B loads/wave halve (800 -> 400 MB
// L2 traffic). MFMA count & per-acc order unchanged -> bit-identical.
__global__ __launch_bounds__(256, 4) void k_gemm1(const float* __restrict__ x,
                                               const ushort_t* __restrict__ w1th,
                                               const ushort_t* __restrict__ w1tl,
                                               const float* __restrict__ a_s,
                                               const float* __restrict__ a_d,
                                               ushort_t* __restrict__ xw1b,
                                               float* __restrict__ al4,
                                               float* __restrict__ ar4, int N) {
    __shared__ __align__(16) unsigned char smem[33792];
    ushort_t* xh = (ushort_t*)smem;
    ushort_t* xl = (ushort_t*)(smem + 16896);
    int r0 = blockIdx.x * 32;
    int tid = threadIdx.x;
    int lane = tid & 63, wv = tid >> 6;
    // ---- stage x -> bf16 hi/lo in LDS ----
    for (int i = tid; i < 2048; i += 256) {
        int r = i >> 6, k4 = (i & 63) << 2;
        float4 v = (r0 + r < N) ? *(const float4*)(x + (size_t)(r0 + r) * 256 + k4)
                                : make_float4(0.f, 0.f, 0.f, 0.f);
        ushort4 h4, l4;
        h4.x = f2bf(v.x); l4.x = f2bf(v.x - bf2f(h4.x));
        h4.y = f2bf(v.y); l4.y = f2bf(v.y - bf2f(h4.y));
        h4.z = f2bf(v.z); l4.z = f2bf(v.z - bf2f(h4.z));
        h4.w = f2bf(v.w); l4.w = f2bf(v.w - bf2f(h4.w));
        *(ushort4*)(&xh[r * 264 + k4]) = h4;
        *(ushort4*)(&xl[r * 264 + k4]) = l4;
    }
    __syncthreads();
    // ---- MFMA K-loop: wave = 32 rows x 64 cols (tiles 4wv..4wv+3) ----
    int jl = lane & 15, q = lane >> 4;
    f32x4 acc[8];                        // [m*4 + t], m=row-group, t=col-tile
    #pragma unroll
    for (int t = 0; t < 8; t++) acc[t] = (f32x4){0.f, 0.f, 0.f, 0.f};
    const ushort_t* xhp0 = &xh[(jl) * 264];
    const ushort_t* xlp0 = &xl[(jl) * 264];
    const ushort_t* xhp1 = &xh[(16 + jl) * 264];
    const ushort_t* xlp1 = &xl[(16 + jl) * 264];
    const ushort_t* bhb = w1th + (size_t)(4 * wv) * 4096 + lane * 8;
    const ushort_t* blb = w1tl + (size_t)(4 * wv) * 4096 + lane * 8;
    #pragma unroll 1
    for (int ks = 0; ks < 8; ks++) {
        int ko = 32 * ks + 8 * q;
        short8v ah0 = *(const short8v*)(xhp0 + ko);
        short8v al0 = *(const short8v*)(xlp0 + ko);
        short8v ah1 = *(const short8v*)(xhp1 + ko);
        short8v al1 = *(const short8v*)(xlp1 + ko);
        #pragma unroll
        for (int t = 0; t < 4; t++) {
            short8v bh = *(const short8v*)(bhb + (t * 8 + ks) * 512);
            short8v bl = *(const short8v*)(blb + (t * 8 + ks) * 512);
            acc[t] = __builtin_amdgcn_mfma_f32_16x16x32_bf16(ah0, bh, acc[t], 0, 0, 0);
            acc[t] = __builtin_amdgcn_mfma_f32_16x16x32_bf16(ah0, bl, acc[t], 0, 0, 0);
            acc[t] = __builtin_amdgcn_mfma_f32_16x16x32_bf16(al0, bh, acc[t], 0, 0, 0);
            acc[4 + t] = __builtin_amdgcn_mfma_f32_16x16x32_bf16(ah1, bh, acc[4 + t], 0, 0, 0);
            acc[4 + t] = __builtin_amdgcn_mfma_f32_16x16x32_bf16(ah1, bl, acc[4 + t], 0, 0, 0);
            acc[4 + t] = __builtin_amdgcn_mfma_f32_16x16x32_bf16(al1, bh, acc[4 + t], 0, 0, 0);
        }
    }
    __syncthreads();                     // everyone done reading xh/xl
    // ---- D frags -> LDS f32 [32][256] ----
    float* outb = (float*)smem;
    #pragma unroll
    for (int m = 0; m < 2; m++) {
        #pragma unroll
        for (int t = 0; t < 4; t++) {
            f32x4 a = acc[m * 4 + t];
            int c = 64 * wv + 16 * t + jl;
            int rb = 16 * m + 4 * q;
            outb[(rb + 0) * 256 + c] = a.x;
            outb[(rb + 1) * 256 + c] = a.y;
            outb[(rb + 2) * 256 + c] = a.z;
            outb[(rb + 3) * 256 + c] = a.w;
        }
    }
    __syncthreads();
    // ---- epilogue (proven structure): al/ar + bf16 repack + coalesced store ----
    int c4 = lane << 2;
    int h = lane >> 4, kk = c4 & 63;
    float4 s4 = *(const float4*)(a_s + h * 64 + kk);
    float4 d4 = *(const float4*)(a_d + h * 64 + kk);
    float4 hv[8];
    #pragma unroll
    for (int t2 = 0; t2 < 8; t2++)
        hv[t2] = *(const float4*)(&outb[(wv + 4 * t2) * 256 + c4]);
    #pragma unroll
    for (int t2 = 0; t2 < 8; t2++) {
        float sl = hv[t2].x * s4.x + hv[t2].y * s4.y + hv[t2].z * s4.z + hv[t2].w * s4.w;
        float sr = hv[t2].x * d4.x + hv[t2].y * d4.y + hv[t2].z * d4.z + hv[t2].w * d4.w;
        #pragma unroll
        for (int o = 1; o < 16; o <<= 1) { sl += __shfl_xor(sl, o); sr += __shfl_xor(sr, o); }
        int r = r0 + wv + 4 * t2;
        if ((lane & 15) == 0 && r < N) {
            al4[(size_t)r * 4 + h] = sl;
            ar4[(size_t)r * 4 + h] = sr;
        }
    }
    __syncthreads();                     // all reads of outb complete
    ushort_t* Ls = (ushort_t*)smem;      // [32][256]
    #pragma unroll
    for (int t2 = 0; t2 < 8; t2++) {
        int rl = wv + 4 * t2;
        Ls[rl * 256 + (kk + 0) * 4 + h] = f2bf(hv[t2].x);
        Ls[rl * 256 + (kk + 1) * 4 + h] = f2bf(hv[t2].y);
        Ls[rl * 256 + (kk + 2) * 4 + h] = f2bf(hv[t2].z);
        Ls[rl * 256 + (kk + 3) * 4 + h] = f2bf(hv[t2].w);
    }
    __syncthreads();
    #pragma unroll
    for (int p = 0; p < 4; p++) {
        int flat = p * 2048 + tid * 8;   // 8 ushorts = 16 B per thread
        int rl = flat >> 8, col = flat & 255;
        int r = r0 + rl;
        if (r < N)
            *(uint4*)(xw1b + (size_t)r * 256 + col) = *(const uint4*)(Ls + flat);
    }
}

__device__ __forceinline__ float4 wexp4(float4 a, float4 arn) {
    float4 w;
    w.x = __expf(lrelu(a.x + arn.x));
    w.y = __expf(lrelu(a.y + arn.y));
    w.z = __expf(lrelu(a.z + arn.z));
    w.w = __expf(lrelu(a.w + arn.w));
    return w;
}

// gather one node's layer-1 aggregation into hrow[0..255] (R7-proven, BYTE-IDENTICAL;
// every structural variation -- deeper in-flight, wide loads, split phases,
// reference params -- spilled to scratch (R2/R8/R11). Do not modify.)
__device__ __forceinline__ void gather1(int n, int lane,
                                        const int* __restrict__ rp,
                                        const int* __restrict__ csr,
                                        const float* __restrict__ al4,
                                        const float* __restrict__ ar4,
                                        const ushort_t* __restrict__ xw1b,
                                        const float* __restrict__ b1,
                                        float4* __restrict__ wb,
                                        int* __restrict__ sb,
                                        float* __restrict__ hrow) {
    int e0 = rp[n], e1 = rp[n + 1];
    float4 arn = *(const float4*)(ar4 + (size_t)n * 4);
    float4 aln = *(const float4*)(al4 + (size_t)n * 4);
    float4 wsf = wexp4(aln, arn);           // self-loop weight
    ushort4 sv = *(const ushort4*)(xw1b + (size_t)n * 256 + lane * 4);
    float a0 = wsf.x * bf2f(sv.x);
    float a1 = wsf.y * bf2f(sv.y);
    float a2 = wsf.z * bf2f(sv.z);
    float a3 = wsf.w * bf2f(sv.w);
    float px = 0.f, py = 0.f, pz = 0.f, pw = 0.f;   // lane-partial weight sums
    for (int cs = e0; cs < e1; cs += CH) {
        int cnt = min(CH, e1 - cs);
        if (lane < cnt) {
            int s = csr[cs + lane];
            float4 A = *(const float4*)(al4 + (size_t)s * 4);
            float4 w = wexp4(A, arn);
            sb[lane] = s;
            wb[lane] = w;
            px += w.x; py += w.y; pz += w.z; pw += w.w;
        }
        // drain LDS writes; per-wave LDS is in-order, no block barrier needed
        asm volatile("s_waitcnt lgkmcnt(0)" ::: "memory");
        int jj = 0;
        for (; jj + 4 <= cnt; jj += 4) {
            int s0 = sb[jj],     s1 = sb[jj + 1];
            int s2 = sb[jj + 2], s3 = sb[jj + 3];
            float4 w0 = wb[jj],     w1 = wb[jj + 1];
            float4 w2 = wb[jj + 2], w3 = wb[jj + 3];
            ushort4 v0 = *(const ushort4*)(xw1b + (size_t)s0 * 256 + lane * 4);
            ushort4 v1 = *(const ushort4*)(xw1b + (size_t)s1 * 256 + lane * 4);
            ushort4 v2 = *(const ushort4*)(xw1b + (size_t)s2 * 256 + lane * 4);
            ushort4 v3 = *(const ushort4*)(xw1b + (size_t)s3 * 256 + lane * 4);
            a0 += w0.x * bf2f(v0.x) + w1.x * bf2f(v1.x) + w2.x * bf2f(v2.x) + w3.x * bf2f(v3.x);
            a1 += w0.y * bf2f(v0.y) + w1.y * bf2f(v1.y) + w2.y * bf2f(v2.y) + w3.y * bf2f(v3.y);
            a2 += w0.z * bf2f(v0.z) + w1.z * bf2f(v1.z) + w2.z * bf2f(v2.z) + w3.z * bf2f(v3.z);
            a3 += w0.w * bf2f(v0.w) + w1.w * bf2f(v1.w) + w2.w * bf2f(v2.w) + w3.w * bf2f(v3.w);
        }
        for (; jj < cnt; jj++) {
            int s = sb[jj];
            float4 w = wb[jj];
            ushort4 v = *(const ushort4*)(xw1b + (size_t)s * 256 + lane * 4);
            a0 += w.x * bf2f(v.x);
            a1 += w.y * bf2f(v.y);
            a2 += w.z * bf2f(v.z);
            a3 += w.w * bf2f(v.w);
        }
    }
    float wx = wave_sum(px) + wsf.x;
    float wy = wave_sum(py) + wsf.y;
    float wz = wave_sum(pz) + wsf.z;
    float ww = wave_sum(pw) + wsf.w;
    hrow[lane]       = eluf(a0 / wx + b1[lane]);
    hrow[64 + lane]  = eluf(a1 / wy + b1[64 + lane]);
    hrow[128 + lane] = eluf(a2 / wz + b1[128 + lane]);
    hrow[192 + lane] = eluf(a3 / ww + b1[192 + lane]);
}

// ------- layer-1 aggregate: 4 nodes per wave, shared-W2 phase 2 (R12-proven) ----
__global__ __launch_bounds__(256, 8) void k_agg4(const int* __restrict__ rp,
                                                 const int* __restrict__ csr,
                                                 const float* __restrict__ al4,
                                                 const float* __restrict__ ar4,
                                                 const ushort_t* __restrict__ xw1b,
                                                 const float* __restrict__ b1,
                                                 const float* __restrict__ W2,
                                                 const float* __restrict__ as2,
                                                 const float* __restrict__ ad2,
                                                 ushort_t* __restrict__ xw2b,
                                                 float* __restrict__ al2,
                                                 float* __restrict__ ar2, int N) {
    __shared__ float hs[4][1024];       // 4 nodes x 256 per wave (16 KB)
    __shared__ float4 wbuf[4][CH];      // shared across sequential gathers
    __shared__ int sbuf[4][CH];
    int wIdx = threadIdx.x >> 6;
    int w = (blockIdx.x * 256 + threadIdx.x) >> 6;
    int lane = threadIdx.x & 63;
    int n0 = 4 * w;
    if (n0 >= N) return;
    #pragma unroll 1
    for (int j = 0; j < 4; j++) {
        int n = n0 + j;
        if (n < N)
            gather1(n, lane, rp, csr, al4, ar4, xw1b, b1, wbuf[wIdx], sbuf[wIdx],
                    &hs[wIdx][256 * j]);
    }
    // drain this wave's hs writes; reads below are same-wave (LDS broadcast)
    asm volatile("s_waitcnt lgkmcnt(0)" ::: "memory");
    {
        bool h1 = (n0 + 1 < N), h2 = (n0 + 2 < N), h3 = (n0 + 3 < N);
        float acc0 = 0.f, acc1 = 0.f, acc2 = 0.f, acc3 = 0.f;
        const float* w2l = W2 + lane;
        #pragma unroll 2
        for (int k4 = 0; k4 < 64; k4++) {
            float u0 = w2l[(size_t)(k4 * 4 + 0) * 64];
            float u1 = w2l[(size_t)(k4 * 4 + 1) * 64];
            float u2 = w2l[(size_t)(k4 * 4 + 2) * 64];
            float u3 = w2l[(size_t)(k4 * 4 + 3) * 64];
            float4 hA = *(const float4*)(&hs[wIdx][k4 * 4]);
            acc0 += hA.x * u0 + hA.y * u1 + hA.z * u2 + hA.w * u3;
            if (h1) {
                float4 hB = *(const float4*)(&hs[wIdx][256 + k4 * 4]);
                acc1 += hB.x * u0 + hB.y * u1 + hB.z * u2 + hB.w * u3;
            }
            if (h2) {
                float4 hC = *(const float4*)(&hs[wIdx][512 + k4 * 4]);
                acc2 += hC.x * u0 + hC.y * u1 + hC.z * u2 + hC.w * u3;
            }
            if (h3) {
                float4 hD = *(const float4*)(&hs[wIdx][768 + k4 * 4]);
                acc3 += hD.x * u0 + hD.y * u1 + hD.z * u2 + hD.w * u3;
            }
        }
        xw2b[(size_t)n0 * 64 + lane] = f2bf(acc0);
        float sl = wave_sum(acc0 * as2[lane]);
        float sr = wave_sum(acc0 * ad2[lane]);
        if (lane == 0) { al2[n0] = sl; ar2[n0] = sr; }
        if (h1) {
            xw2b[(size_t)(n0 + 1) * 64 + lane] = f2bf(acc1);
            float sl1 = wave_sum(acc1 * as2[lane]);
            float sr1 = wave_sum(acc1 * ad2[lane]);
            if (lane == 0) { al2[n0 + 1] = sl1; ar2[n0 + 1] = sr1; }
        }
        if (h2) {
            xw2b[(size_t)(n0 + 2) * 64 + lane] = f2bf(acc2);
            float sl2 = wave_sum(acc2 * as2[lane]);
            float sr2 = wave_sum(acc2 * ad2[lane]);
            if (lane == 0) { al2[n0 + 2] = sl2; ar2[n0 + 2] = sr2; }
        }
        if (h3) {
            xw2b[(size_t)(n0 + 3) * 64 + lane] = f2bf(acc3);
            float sl3 = wave_sum(acc3 * as2[lane]);
            float sr3 = wave_sum(acc3 * ad2[lane]);
            if (lane == 0) { al2[n0 + 3] = sl3; ar2[n0 + 3] = sr3; }
        }
    }
}

// ------- layer-2 aggregate: two-phase, 8-deep gather, bf16 rows (R7-proven) -----
__global__ __launch_bounds__(256, 8) void k_agg2(const int* __restrict__ rp,
                                                 const int* __restrict__ csr,
                                                 const float* __restrict__ al2,
                                                 const float* __restrict__ ar2,
                                                 const ushort_t* __restrict__ xw2b,
                                                 const float* __restrict__ b2,
                                                 float* __restrict__ hout, int N) {
    __shared__ float wbuf[4][CH];
    __shared__ int sbuf[4][CH];
    int wIdx = threadIdx.x >> 6;
    int n = (blockIdx.x * 256 + threadIdx.x) >> 6;
    int lane = threadIdx.x & 63;
    if (n >= N) return;
    int e0 = rp[n], e1 = rp[n + 1];
    float arn = ar2[n];
    float wself = __expf(lrelu(al2[n] + arn));
    float acc = wself * bf2f(xw2b[(size_t)n * 64 + lane]);
    float p = 0.f;
    for (int cs = e0; cs < e1; cs += CH) {
        int cnt = min(CH, e1 - cs);
        if (lane < cnt) {
            int s = csr[cs + lane];
            float w = __expf(lrelu(al2[s] + arn));
            sbuf[wIdx][lane] = s;
            wbuf[wIdx][lane] = w;
            p += w;
        }
        asm volatile("s_waitcnt lgkmcnt(0)" ::: "memory");
        int jj = 0;
        for (; jj + 8 <= cnt; jj += 8) {
            int s0 = sbuf[wIdx][jj],     s1 = sbuf[wIdx][jj + 1];
            int s2 = sbuf[wIdx][jj + 2], s3 = sbuf[wIdx][jj + 3];
            int s4 = sbuf[wIdx][jj + 4], s5 = sbuf[wIdx][jj + 5];
            int s6 = sbuf[wIdx][jj + 6], s7 = sbuf[wIdx][jj + 7];
            float w0 = wbuf[wIdx][jj],     w1 = wbuf[wIdx][jj + 1];
            float w2 = wbuf[wIdx][jj + 2], w3 = wbuf[wIdx][jj + 3];
            float w4 = wbuf[wIdx][jj + 4], w5 = wbuf[wIdx][jj + 5];
            float w6 = wbuf[wIdx][jj + 6], w7 = wbuf[wIdx][jj + 7];
            float v0 = bf2f(xw2b[(size_t)s0 * 64 + lane]);
            float v1 = bf2f(xw2b[(size_t)s1 * 64 + lane]);
            float v2 = bf2f(xw2b[(size_t)s2 * 64 + lane]);
            float v3 = bf2f(xw2b[(size_t)s3 * 64 + lane]);
            float v4 = bf2f(xw2b[(size_t)s4 * 64 + lane]);
            float v5 = bf2f(xw2b[(size_t)s5 * 64 + lane]);
            float v6 = bf2f(xw2b[(size_t)s6 * 64 + lane]);
            float v7 = bf2f(xw2b[(size_t)s7 * 64 + lane]);
            acc += w0 * v0 + w1 * v1 + w2 * v2 + w3 * v3;
            acc += w4 * v4 + w5 * v5 + w6 * v6 + w7 * v7;
        }
        for (; jj + 4 <= cnt; jj += 4) {
            int s0 = sbuf[wIdx][jj],     s1 = sbuf[wIdx][jj + 1];
            int s2 = sbuf[wIdx][jj + 2], s3 = sbuf[wIdx][jj + 3];
            float w0 = wbuf[wIdx][jj],     w1 = wbuf[wIdx][jj + 1];
            float w2 = wbuf[wIdx][jj + 2], w3 = wbuf[wIdx][jj + 3];
            float v0 = bf2f(xw2b[(size_t)s0 * 64 + lane]);
            float v1 = bf2f(xw2b[(size_t)s1 * 64 + lane]);
            float v2 = bf2f(xw2b[(size_t)s2 * 64 + lane]);
            float v3 = bf2f(xw2b[(size_t)s3 * 64 + lane]);
            acc += w0 * v0 + w1 * v1 + w2 * v2 + w3 * v3;
        }
        for (; jj < cnt; jj++) {
            int s = sbuf[wIdx][jj];
            acc += wbuf[wIdx][jj] * bf2f(xw2b[(size_t)s * 64 + lane]);
        }
    }
    float wsum = wave_sum(p) + wself;
    hout[(size_t)n * 64 + lane] = eluf(acc / wsum + b2[lane]);
}

// ------- mean pool (batch sorted, 32 nodes/wave) + logits -----------------------
__global__ __launch_bounds__(256) void k_pool(const float* __restrict__ h2,
                                              const int* __restrict__ batch,
                                              float* __restrict__ pooled,
                                              float* __restrict__ cnt, int N) {
    int wave = (blockIdx.x * 256 + threadIdx.x) >> 6;
    int lane = threadIdx.x & 63;
    int n0 = wave * 32;
    if (n0 >= N) return;
    int n1 = min(n0 + 32, N);
    float acc = 0.f; int cl = 0;
    int curg = batch[n0];
    for (int n = n0; n < n1; n++) {
        int g = batch[n];
        if (g != curg) {
            atomicAdd(&pooled[curg * 64 + lane], acc);
            if (lane == 0) atomicAdd(&cnt[curg], (float)cl);
            acc = 0.f; cl = 0; curg = g;
        }
        acc += h2[(size_t)n * 64 + lane];
        cl++;
    }
    atomicAdd(&pooled[curg * 64 + lane], acc);
    if (lane == 0) atomicAdd(&cnt[curg], (float)cl);
}

__global__ __launch_bounds__(64) void k_logits(const float* __restrict__ pooled,
                                               const float* __restrict__ cnt,
                                               const float* __restrict__ fcW,
                                               const float* __restrict__ fcb,
                                               float* __restrict__ out) {
    int t = threadIdx.x;
    if (t >= NG * 2) return;
    int g = t >> 1, o = t & 1;
    float invc = 1.f / fmaxf(cnt[g], 1.f);
    float s = 0.f;
    for (int c = 0; c < 64; c++)
        s += pooled[g * 64 + c] * invc * fcW[c * 2 + o];
    s += fcb[o];
    out[g * 2 + o] = s;
}

extern "C" void kernel_launch(void* const* d_in, const int* in_sizes, int n_in,
                              void* d_out, int out_size, void* d_ws, size_t ws_size,
                              hipStream_t stream) {
    const float* x     = (const float*)d_in[0];
    const int*   ei    = (const int*)d_in[1];
    const int*   batch = (const int*)d_in[2];
    const float* W1    = (const float*)d_in[3];
    const float* as1   = (const float*)d_in[4];
    const float* ad1   = (const float*)d_in[5];
    const float* b1    = (const float*)d_in[6];
    const float* W2    = (const float*)d_in[7];
    const float* as2   = (const float*)d_in[8];
    const float* ad2   = (const float*)d_in[9];
    const float* b2v   = (const float*)d_in[10];
    const float* fcW   = (const float*)d_in[11];
    const float* fcb   = (const float*)d_in[12];
    float* out = (float*)d_out;

    const int N = in_sizes[2];       // 50000
    const int E = in_sizes[1] / 2;   // 800000
    const size_t nv  = (size_t)N * 64;
    const size_t nv4 = (size_t)N * 256;
    const int SB = (N + 1023) / 1024;

    // workspace layout: bf16 xw1, bf16 xw2, then floats, then ints (~36 MB)
    ushort_t* xw1b = (ushort_t*)d_ws;                      // nv4 ushorts (25.6 MB)
    ushort_t* xw2b   = xw1b + nv4;                         // nv ushorts (6.4 MB)
    float*    al4    = (float*)(xw2b + nv);                // N*4
    float*    ar4    = al4 + (size_t)N * 4;                // N*4
    float*    al2    = ar4 + (size_t)N * 4;                // N
    float*    ar2    = al2 + N;                            // N
    float*    pooled = ar2 + N;                            // 512
    float*    cnt    = pooled + NG * 64;                   // 8
    int*      deg    = (int*)(cnt + 8);                    // N
    int*      rp     = deg + N;                            // N+1
    int*      cur    = rp + N + 1;                         // N
    int*      csr    = cur + N;                            // E
    int*      bsum   = csr + E;                            // SB
    int*      boff   = bsum + 64;                          // SB
    // W1 in fragment order, bf16 hi/lo, 256-B aligned
    ushort_t* w1th = (ushort_t*)(((uintptr_t)(boff + 64) + 255) & ~(uintptr_t)255);
    ushort_t* w1tl = w1th + 65536;                         // 128 KB each

    const int gE  = (E + 255) / 256;
    const int gB4 = (N + 15) / 16;   // 4 nodes per wave, 16 per block
    const int gB2 = (N + 3) / 4;
    const int gG1 = (N + 31) / 32;   // 32 rows per block
    const int pw  = (N + 31) / 32;
    const int gP  = (pw * 64 + 255) / 256;

    // ---- CSR build + weight prep ----
    hipMemsetAsync(deg, 0, (size_t)N * sizeof(int), stream);
    k_hist<<<gE, 256, 0, stream>>>(ei, deg, E);
    k_scanA<<<SB, 256, 0, stream>>>(deg, bsum, N);
    k_scanB<<<1, 64, 0, stream>>>(bsum, boff, rp + N, SB);
    k_scanC<<<SB, 256, 0, stream>>>(deg, boff, rp, cur, N);
    k_fill<<<gE, 256, 0, stream>>>(ei, cur, csr, E);
    k_w1t<<<128, 256, 0, stream>>>(W1, w1th, w1tl);

    // ---- layer 1 ----
    k_gemm1<<<gG1, 256, 0, stream>>>(x, w1th, w1tl, as1, ad1, xw1b, al4, ar4, N);
    k_agg4<<<gB4, 256, 0, stream>>>(rp, csr, al4, ar4, xw1b, b1, W2, as2, ad2,
                                    xw2b, al2, ar2, N);

    // ---- layer 2 ----
    k_agg2<<<gB2, 256, 0, stream>>>(rp, csr, al2, ar2, xw2b, b2v, out, N);

    // ---- pooling + logits ----
    hipMemsetAsync(pooled, 0, (NG * 64 + NG) * sizeof(float), stream);
    k_pool<<<gP, 256, 0, stream>>>(out, batch, pooled, cnt, N);
    k_logits<<<1, 64, 0, stream>>>(pooled, cnt, fcW, fcb, out + nv);
}